// Round 1
// baseline (130.106 us; speedup 1.0000x reference)
//
#include <hip/hip_runtime.h>

// Problem constants (fixed by reference)
#define M_TOTAL 8192
#define KDIM 1024
#define TASKS 20
#define SBUF 256
#define NTOT (TASKS * SBUF)

// GEMM tile config
#define BM 128
#define BN 256
#define BK 32

typedef __bf16 bf16x8 __attribute__((ext_vector_type(8)));
typedef float f32x4 __attribute__((ext_vector_type(4)));

// float -> bf16 round-to-nearest-even (no NaN handling needed here)
__device__ __forceinline__ unsigned short f2bf(float f) {
  unsigned int x = __float_as_uint(f);
  x += 0x7fffU + ((x >> 16) & 1U);
  return (unsigned short)(x >> 16);
}

__device__ __forceinline__ void gload_lds16(const unsigned short* g, unsigned short* l) {
  __builtin_amdgcn_global_load_lds((const __attribute__((address_space(1))) void*)g,
                                   (__attribute__((address_space(3))) void*)l,
                                   16, 0, 0);
}

// One block per row: L2-normalize a 1024-float row, emit bf16.
__global__ __launch_bounds__(256) void norm_rows_kernel(const float* __restrict__ in,
                                                        unsigned short* __restrict__ out) {
  const int row = blockIdx.x;
  const int tid = threadIdx.x;
  const float4 v = ((const float4*)(in + (size_t)row * KDIM))[tid];
  float s = v.x * v.x + v.y * v.y + v.z * v.z + v.w * v.w;
#pragma unroll
  for (int off = 32; off >= 1; off >>= 1) s += __shfl_xor(s, off, 64);
  __shared__ float part[4];
  if ((tid & 63) == 0) part[tid >> 6] = s;
  __syncthreads();
  s = part[0] + part[1] + part[2] + part[3];
  const float sc = rsqrtf(s);
  ushort4 o;
  o.x = f2bf(v.x * sc);
  o.y = f2bf(v.y * sc);
  o.z = f2bf(v.z * sc);
  o.w = f2bf(v.w * sc);
  ((ushort4*)(out + (size_t)row * KDIM))[tid] = o;
}

// C = Xn * Wn^T restricted to one task's 256 columns, fused
// dist = sqrt(max(2 - 2*dot, EPS)) and min over the 256 columns.
// Block: 512 threads = 8 waves (2 row-waves x 4 col-waves), each wave 64x64 out.
__global__ __launch_bounds__(512, 2) void gemm_min_kernel(const unsigned short* __restrict__ Xn,
                                                          const unsigned short* __restrict__ Wn,
                                                          float* __restrict__ out) {
  __shared__ __align__(16) unsigned short As[BM * BK];  // 8 KB  [row][k]
  __shared__ __align__(16) unsigned short Bs[BN * BK];  // 16 KB [col][k]
  __shared__ float red[BM][4];

  const int tid = threadIdx.x;
  const int lane = tid & 63;
  const int w = tid >> 6;   // 0..7
  const int wr = w >> 2;    // 0..1 (row group)
  const int wc = w & 3;     // 0..3 (col group)
  const int lgrp = lane >> 4;  // k-group 0..3
  const int lrow = lane & 15;

  const int rowBase = blockIdx.x * BM;
  const int task = blockIdx.y;
  const unsigned short* Wt = Wn + (size_t)task * SBUF * KDIM;

  // staging: thread t covers bytes [t*16, t*16+16) of each 8KB half-tile.
  // LDS dest = wave-uniform base + lane*16 (global_load_lds constraint).
  const int srow = tid >> 2;          // 0..127
  const int skof = (tid & 3) * 8;     // k offset in elements
  const unsigned short* gA = Xn + (size_t)(rowBase + srow) * KDIM + skof;
  const unsigned short* gB0 = Wt + (size_t)srow * KDIM + skof;
  const unsigned short* gB1 = Wt + (size_t)(128 + srow) * KDIM + skof;
  unsigned short* lA = &As[tid * 8];
  unsigned short* lB0 = &Bs[tid * 8];
  unsigned short* lB1 = &Bs[4096 + tid * 8];

  f32x4 acc[4][4] = {};

  for (int k0 = 0; k0 < KDIM; k0 += BK) {
    __syncthreads();  // previous iteration's ds_reads done before overwrite
    gload_lds16(gA + k0, lA);
    gload_lds16(gB0 + k0, lB0);
    gload_lds16(gB1 + k0, lB1);
    __syncthreads();  // implies s_waitcnt vmcnt(0): staged data visible

    bf16x8 af[4], bfr[4];
#pragma unroll
    for (int m = 0; m < 4; ++m)
      af[m] = *(const bf16x8*)&As[(wr * 64 + m * 16 + lrow) * BK + lgrp * 8];
#pragma unroll
    for (int n = 0; n < 4; ++n)
      bfr[n] = *(const bf16x8*)&Bs[(wc * 64 + n * 16 + lrow) * BK + lgrp * 8];
#pragma unroll
    for (int m = 0; m < 4; ++m)
#pragma unroll
      for (int n = 0; n < 4; ++n)
        acc[m][n] = __builtin_amdgcn_mfma_f32_16x16x32_bf16(af[m], bfr[n], acc[m][n], 0, 0, 0);
  }

  // Epilogue. C/D layout (m89-verified): col = lane&15, row = (lane>>4)*4 + reg.
  // Per (m, reg): one output row; min over this wave's 64 columns.
#pragma unroll
  for (int m = 0; m < 4; ++m) {
#pragma unroll
    for (int r = 0; r < 4; ++r) {
      float v = 1e30f;
#pragma unroll
      for (int n = 0; n < 4; ++n) {
        float d = sqrtf(fmaxf(2.0f - 2.0f * acc[m][n][r], 1e-12f));
        v = fminf(v, d);
      }
      // reduce across the 16 column-lanes (bits 0..3 of lane)
      v = fminf(v, __shfl_xor(v, 1, 64));
      v = fminf(v, __shfl_xor(v, 2, 64));
      v = fminf(v, __shfl_xor(v, 4, 64));
      v = fminf(v, __shfl_xor(v, 8, 64));
      if (lrow == 0) red[wr * 64 + m * 16 + lgrp * 4 + r][wc] = v;
    }
  }
  __syncthreads();
  if (tid < BM) {
    float v = fminf(fminf(red[tid][0], red[tid][1]), fminf(red[tid][2], red[tid][3]));
    out[(size_t)(rowBase + tid) * TASKS + task] = -v;
  }
}

extern "C" void kernel_launch(void* const* d_in, const int* in_sizes, int n_in,
                              void* d_out, int out_size, void* d_ws, size_t ws_size,
                              hipStream_t stream) {
  const float* X = (const float*)d_in[0];   // (8192, 1024) fp32
  const float* W = (const float*)d_in[1];   // (5120, 1024) fp32
  float* out = (float*)d_out;               // (8192, 20) fp32

  unsigned short* Xn = (unsigned short*)d_ws;                                  // 16.78 MB
  unsigned short* Wn = (unsigned short*)((char*)d_ws + (size_t)M_TOTAL * KDIM * 2);  // 10.49 MB

  norm_rows_kernel<<<M_TOTAL, 256, 0, stream>>>(X, Xn);
  norm_rows_kernel<<<NTOT, 256, 0, stream>>>(W, Wn);
  gemm_min_kernel<<<dim3(M_TOTAL / BM, TASKS), 512, 0, stream>>>(Xn, Wn, out);
}

// Round 2
// 120.987 us; speedup vs baseline: 1.0754x; 1.0754x over previous
//
#include <hip/hip_runtime.h>

#define M_TOTAL 8192
#define KDIM 1024
#define TASKS 20
#define SBUF 256

typedef __bf16 bf16x8 __attribute__((ext_vector_type(8)));
typedef float f32x4 __attribute__((ext_vector_type(4)));

__device__ __forceinline__ unsigned short f2bf(float f) {
  unsigned int x = __float_as_uint(f);
  x += 0x7fffU + ((x >> 16) & 1U);
  return (unsigned short)(x >> 16);
}

__device__ __forceinline__ void gload_lds16(const unsigned short* g, char* l) {
  __builtin_amdgcn_global_load_lds((const __attribute__((address_space(1))) void*)g,
                                   (__attribute__((address_space(3))) void*)l, 16, 0, 0);
}

#define FENCE() asm volatile("" ::: "memory")
#define BAR() do { FENCE(); __builtin_amdgcn_s_barrier(); FENCE(); } while (0)
#define LGKM0() asm volatile("s_waitcnt lgkmcnt(0)" ::: "memory")
#define VMC(n) asm volatile("s_waitcnt vmcnt(" #n ")" ::: "memory")

// One block per row: L2-normalize a 1024-float row, emit bf16.
__global__ __launch_bounds__(256) void norm_rows_kernel(const float* __restrict__ in,
                                                        unsigned short* __restrict__ out) {
  const int row = blockIdx.x;
  const int tid = threadIdx.x;
  const float4 v = ((const float4*)(in + (size_t)row * KDIM))[tid];
  float s = v.x * v.x + v.y * v.y + v.z * v.z + v.w * v.w;
#pragma unroll
  for (int off = 32; off >= 1; off >>= 1) s += __shfl_xor(s, off, 64);
  __shared__ float part[4];
  if ((tid & 63) == 0) part[tid >> 6] = s;
  __syncthreads();
  s = part[0] + part[1] + part[2] + part[3];
  const float sc = rsqrtf(s);
  ushort4 o;
  o.x = f2bf(v.x * sc);
  o.y = f2bf(v.y * sc);
  o.z = f2bf(v.z * sc);
  o.w = f2bf(v.w * sc);
  ((ushort4*)(out + (size_t)row * KDIM))[tid] = o;
}

// LDS map (bytes): A bufs [0, 64K): buf*32768 + row*128 + slot16
//                  B bufs [64K, 128K): 65536 + buf*32768 + row*128 + slot16
//                  red    [128K, 132K)
// XOR swizzle: physical 16B slot = logical_slot ^ (row & 7). global_load_lds
// writes linearly, so the SOURCE is inverse-permuted per thread (rule #21).
#define RDA_(P, mh, m) (*(const bf16x8*)((P) + B_ * 32768 + (mh) * 8192 + (m) * 2048))
#define RDB_(P, n)     (*(const bf16x8*)((P) + B_ * 32768 + (n) * 2048))
#define STG_A_(bf, hf, kb) do { \
    gload_lds16(pA + (hf) * 131072 + (kb), sdA + (bf) * 32768 + (hf) * 16384); \
    gload_lds16(pA + (hf) * 131072 + 65536 + (kb), sdA + (bf) * 32768 + (hf) * 16384 + 8192); \
  } while (0)
#define STG_B_(bf, hf, kb) do { \
    gload_lds16(pB + (hf) * 131072 + (kb), sdB + (bf) * 32768 + (hf) * 16384); \
    gload_lds16(pB + (hf) * 131072 + 65536 + (kb), sdB + (bf) * 32768 + (hf) * 16384 + 8192); \
  } while (0)
#define MFMA_(a, bb, c) (c) = __builtin_amdgcn_mfma_f32_16x16x32_bf16((a), (bb), (c), 0, 0, 0)

// One K-tile (BK=64) = 4 phases. Stage ledger (per tile t, buf b=t&1):
//  P1: dsA mh0(8) + dsB nh0(4); stage A0(t+1)->buf 1-b
//  P2: dsB nh1(4);              stage A1(t+1)->buf 1-b
//  P3: dsA mh1(8);              stage B0(t+2)->buf b   (B region dead since P2)
//  P4: (reuse);                 stage B1(t+2)->buf b; vmcnt(4) -> tile t+1 resident
template <int B_>
__device__ __forceinline__ void tile_step(int kt, f32x4 (&acc)[8][4],
                                          const unsigned short* pA, const unsigned short* pB,
                                          char* sdA, char* sdB,
                                          const char* aB0, const char* aB1,
                                          const char* bB0, const char* bB1) {
  const int kA = (kt + 1 < 16) ? (kt + 1) * 64 : 0;            // wrap: harmless garbage
  const int kB = (kt + 2 < 16) ? (kt + 2) * 64 : (kt - 14) * 64;
  bf16x8 aF[4][2], bF[4][2];

  // ---- P1: quadrant (mh0, nh0) ----
#pragma unroll
  for (int m = 0; m < 4; ++m) { aF[m][0] = RDA_(aB0, 0, m); aF[m][1] = RDA_(aB1, 0, m); }
#pragma unroll
  for (int n = 0; n < 2; ++n) { bF[n][0] = RDB_(bB0, n); bF[n][1] = RDB_(bB1, n); }
  STG_A_(1 - B_, 0, kA);
  BAR(); LGKM0();
  __builtin_amdgcn_s_setprio(1);
#pragma unroll
  for (int m = 0; m < 4; ++m)
#pragma unroll
    for (int n = 0; n < 2; ++n) { MFMA_(aF[m][0], bF[n][0], acc[m][n]); MFMA_(aF[m][1], bF[n][1], acc[m][n]); }
  __builtin_amdgcn_s_setprio(0);
  BAR();

  // ---- P2: quadrant (mh0, nh1) ----
#pragma unroll
  for (int n = 2; n < 4; ++n) { bF[n][0] = RDB_(bB0, n); bF[n][1] = RDB_(bB1, n); }
  STG_A_(1 - B_, 1, kA);
  BAR(); LGKM0();
  __builtin_amdgcn_s_setprio(1);
#pragma unroll
  for (int m = 0; m < 4; ++m)
#pragma unroll
    for (int n = 2; n < 4; ++n) { MFMA_(aF[m][0], bF[n][0], acc[m][n]); MFMA_(aF[m][1], bF[n][1], acc[m][n]); }
  __builtin_amdgcn_s_setprio(0);
  BAR();

  // ---- P3: quadrant (mh1, nh1) ----
#pragma unroll
  for (int m = 0; m < 4; ++m) { aF[m][0] = RDA_(aB0, 1, m); aF[m][1] = RDA_(aB1, 1, m); }
  STG_B_(B_, 0, kB);
  BAR(); LGKM0();
  __builtin_amdgcn_s_setprio(1);
#pragma unroll
  for (int m = 0; m < 4; ++m)
#pragma unroll
    for (int n = 2; n < 4; ++n) { MFMA_(aF[m][0], bF[n][0], acc[4 + m][n]); MFMA_(aF[m][1], bF[n][1], acc[4 + m][n]); }
  __builtin_amdgcn_s_setprio(0);
  BAR();

  // ---- P4: quadrant (mh1, nh0) ----
  STG_B_(B_, 1, kB);
  VMC(4);                      // next tile's 4 half-tiles done; 2 halves stay in flight
  BAR();
  __builtin_amdgcn_s_setprio(1);
#pragma unroll
  for (int m = 0; m < 4; ++m)
#pragma unroll
    for (int n = 0; n < 2; ++n) { MFMA_(aF[m][0], bF[n][0], acc[4 + m][n]); MFMA_(aF[m][1], bF[n][1], acc[4 + m][n]); }
  __builtin_amdgcn_s_setprio(0);
  BAR();
}

// 256x256 tile per block, one task per block column. 512 threads = 8 waves (2Mx4N),
// each wave owns a 128x64 sub-tile (8x4 16x16 frags). Fused sqrt+min epilogue.
__global__ __launch_bounds__(512, 2) void gemm_min_kernel(const unsigned short* __restrict__ Xn,
                                                          const unsigned short* __restrict__ Wn,
                                                          float* __restrict__ out) {
  __shared__ __align__(16) char sm[135168];

  const int tid = threadIdx.x;
  const int lane = tid & 63;
  const int w = tid >> 6, wr = w >> 2, wc = w & 3;
  const int lrow = lane & 15, lgrp = lane >> 4;

  // bijective XCD swizzle (640 % 8 == 0)
  const int o = blockIdx.x;
  const int swz = (o & 7) * 80 + (o >> 3);
  const int mblk = swz & 31, task = swz >> 5;
  const int rowBase = mblk * 256;

  // staging: thread t -> linear LDS byte t*16 (row=t>>3 of the half, phys slot=t&7);
  // source slot inverse-swizzled so that swizzled reads see G[row][slot].
  const int srow = tid >> 3;
  const int sslot = (tid & 7) ^ ((tid >> 3) & 7);
  const unsigned short* pA = Xn + (size_t)(rowBase + srow) * KDIM + sslot * 8;
  const unsigned short* pB = Wn + (size_t)task * SBUF * KDIM + (size_t)srow * KDIM + sslot * 8;
  char* const sdA = sm + tid * 16;
  char* const sdB = sm + 65536 + tid * 16;

  // ds_read lane bases; kk=1 slot = kk=0 slot XOR 4 -> byte XOR 64
  const int sx0 = (lgrp ^ (lrow & 7)) * 16;
  const char* aB0 = sm + (wr * 128 + lrow) * 128 + sx0;
  const char* aB1 = sm + (wr * 128 + lrow) * 128 + (sx0 ^ 64);
  const char* bB0 = sm + 65536 + (wc * 64 + lrow) * 128 + sx0;
  const char* bB1 = sm + 65536 + (wc * 64 + lrow) * 128 + (sx0 ^ 64);

  f32x4 acc[8][4] = {};

  // prologue: tile0 fully + tile1 B halves; drain to 4 loads -> tile0 resident
  STG_A_(0, 0, 0); STG_A_(0, 1, 0); STG_B_(0, 0, 0); STG_B_(0, 1, 0);
  STG_B_(1, 0, 64); STG_B_(1, 1, 64);
  VMC(4);
  BAR();

  for (int kt = 0; kt < 16; kt += 2) {
    tile_step<0>(kt, acc, pA, pB, sdA, sdB, aB0, aB1, bB0, bB1);
    tile_step<1>(kt + 1, acc, pA, pB, sdA, sdB, aB0, aB1, bB0, bB1);
  }

  // epilogue: drain wrapped garbage stages, then fused max-dot -> min-dist
  VMC(0);
  BAR();
  float (*red)[4] = (float (*)[4])(sm + 131072);
#pragma unroll
  for (int mi = 0; mi < 8; ++mi) {
#pragma unroll
    for (int r = 0; r < 4; ++r) {
      float v = fmaxf(fmaxf(acc[mi][0][r], acc[mi][1][r]), fmaxf(acc[mi][2][r], acc[mi][3][r]));
      v = fmaxf(v, __shfl_xor(v, 1, 64));
      v = fmaxf(v, __shfl_xor(v, 2, 64));
      v = fmaxf(v, __shfl_xor(v, 4, 64));
      v = fmaxf(v, __shfl_xor(v, 8, 64));
      if (lrow == 0) red[wr * 128 + mi * 16 + lgrp * 4 + r][wc] = v;
    }
  }
  BAR();
  if (tid < 256) {
    float v = fmaxf(fmaxf(red[tid][0], red[tid][1]), fmaxf(red[tid][2], red[tid][3]));
    float d = sqrtf(fmaxf(2.0f - 2.0f * v, 1e-12f));
    out[(size_t)(rowBase + tid) * TASKS + task] = -d;
  }
}

extern "C" void kernel_launch(void* const* d_in, const int* in_sizes, int n_in,
                              void* d_out, int out_size, void* d_ws, size_t ws_size,
                              hipStream_t stream) {
  const float* X = (const float*)d_in[0];   // (8192, 1024) fp32
  const float* W = (const float*)d_in[1];   // (5120, 1024) fp32
  float* out = (float*)d_out;               // (8192, 20) fp32

  unsigned short* Xn = (unsigned short*)d_ws;
  unsigned short* Wn = (unsigned short*)((char*)d_ws + (size_t)M_TOTAL * KDIM * 2);

  norm_rows_kernel<<<M_TOTAL, 256, 0, stream>>>(X, Xn);
  norm_rows_kernel<<<TASKS * SBUF, 256, 0, stream>>>(W, Wn);
  gemm_min_kernel<<<dim3(M_TOTAL / 256 * TASKS), 512, 0, stream>>>(Xn, Wn, out);
}

// Round 3
// 118.045 us; speedup vs baseline: 1.1022x; 1.0249x over previous
//
#include <hip/hip_runtime.h>

#define M_TOTAL 8192
#define KDIM 1024
#define TASKS 20
#define SBUF 256

typedef __bf16 bf16x8 __attribute__((ext_vector_type(8)));
typedef float f32x4 __attribute__((ext_vector_type(4)));

__device__ __forceinline__ unsigned short f2bf(float f) {
  unsigned int x = __float_as_uint(f);
  x += 0x7fffU + ((x >> 16) & 1U);
  return (unsigned short)(x >> 16);
}

__device__ __forceinline__ void gload_lds16(const unsigned short* g, char* l) {
  __builtin_amdgcn_global_load_lds((const __attribute__((address_space(1))) void*)g,
                                   (__attribute__((address_space(3))) void*)l, 16, 0, 0);
}

#define FENCE() asm volatile("" ::: "memory")
#define BAR() do { FENCE(); __builtin_amdgcn_s_barrier(); FENCE(); } while (0)
#define LGKM0() asm volatile("s_waitcnt lgkmcnt(0)" ::: "memory")
#define VMC(n) asm volatile("s_waitcnt vmcnt(" #n ")" ::: "memory")
#define SCHED0() __builtin_amdgcn_sched_barrier(0)
#define MFMA_(a, bb, c) (c) = __builtin_amdgcn_mfma_f32_16x16x32_bf16((a), (bb), (c), 0, 0, 0)

// One block per row: L2-normalize a 1024-float row, emit bf16.
__global__ __launch_bounds__(256) void norm_rows_kernel(const float* __restrict__ in,
                                                        unsigned short* __restrict__ out) {
  const int row = blockIdx.x;
  const int tid = threadIdx.x;
  const float4 v = ((const float4*)(in + (size_t)row * KDIM))[tid];
  float s = v.x * v.x + v.y * v.y + v.z * v.z + v.w * v.w;
#pragma unroll
  for (int off = 32; off >= 1; off >>= 1) s += __shfl_xor(s, off, 64);
  __shared__ float part[4];
  if ((tid & 63) == 0) part[tid >> 6] = s;
  __syncthreads();
  s = part[0] + part[1] + part[2] + part[3];
  const float sc = rsqrtf(s);
  ushort4 o;
  o.x = f2bf(v.x * sc);
  o.y = f2bf(v.y * sc);
  o.z = f2bf(v.z * sc);
  o.w = f2bf(v.w * sc);
  ((ushort4*)(out + (size_t)row * KDIM))[tid] = o;
}

__global__ __launch_bounds__(256) void init_out_kernel(float* __restrict__ out) {
  const int i = blockIdx.x * 256 + threadIdx.x;
  if (i < M_TOTAL * TASKS) out[i] = -1e30f;
}

// 256(M)x128(N) tile, BK=32, 512 thr = 8 waves (4M x 2N), wave 64x64, 2 blocks/CU.
// LDS (bytes): A bufs [0,32K) 2x16K; B bufs [32K,49152) 2x8K; red [49152,51200).
// Pair-row swizzle: rows 2q,2q+1 share a 128B block; granule(row,s) =
// (((row&1)<<2)|s) ^ (q&7). Stage dest is linear (thread t -> byte t*16);
// the global SOURCE is inverse-permuted (rule #21).
__global__ __launch_bounds__(512, 4) void gemm_min_kernel(const unsigned short* __restrict__ Xn,
                                                          const unsigned short* __restrict__ Wn,
                                                          float* __restrict__ out) {
  __shared__ __align__(16) char sm[51200];

  const int tid = threadIdx.x;
  const int lane = tid & 63;
  const int w = tid >> 6, wr = w >> 1, wc = w & 1;
  const int lrow = lane & 15, lgrp = lane >> 4;

  // 1280 blocks: each XCD owns 5 nblk columns (B 1.25MB L2-resident),
  // 8-mblk supertiles, m-fastest for tight B temporal reuse.
  const int o = blockIdx.x;
  const int xcd = o & 7, idx = o >> 3;
  const int st = idx / 40, r = idx % 40;
  const int mblk = st * 8 + (r & 7);
  const int nblk = xcd * 5 + (r >> 3);
  const int rowBase = mblk * 256;
  const int task = nblk >> 1;
  const int col0 = task * SBUF + (nblk & 1) * 128;

  // staging source decode (inverse of the pair-row swizzle)
  const int q = tid >> 3, p = tid & 7;
  const int s8 = p ^ (q & 7);
  const int rowl = q * 2 + (s8 >> 2);
  const int koff = (s8 & 3) * 8;
  const unsigned short* pA = Xn + (size_t)(rowBase + rowl) * KDIM + koff;
  const unsigned short* pB = Wn + (size_t)(col0 + rowl) * KDIM + koff;
  char* const sdA = sm + tid * 16;
  char* const sdB = sm + 32768 + tid * 16;

  // ds_read lane bases (row = r0 + lrow, r0 mult of 16 -> (row>>1)&7 = lrow>>1)
  const int gran = ((((lrow & 1) << 2) | lgrp) ^ (lrow >> 1)) * 16;
  const int aBase = wr * 4096 + (lrow >> 1) * 128 + gran;
  const int bBase = 32768 + wc * 4096 + (lrow >> 1) * 128 + gran;

  f32x4 acc[4][4] = {};

#define STG(B_, kSt) do { \
    gload_lds16(pA + (kSt), sdA + (B_) * 16384); \
    gload_lds16(pA + 131072 + (kSt), sdA + (B_) * 16384 + 8192); \
    gload_lds16(pB + (kSt), sdB + (B_) * 8192); \
  } while (0)

  // prologue: tile0 -> buf0, tile1 -> buf1; drain tile0, tile1 in flight
  STG(0, 0);
  STG(1, 32);
  VMC(3); SCHED0();
  BAR();

  // Per K-tile: Ph1 {8 ds_read, MFMA n-half0, lgkm-drain, BAR};
  //             Ph2 {stage t+2 -> own buf, VMC(3) [t+1 resident], MFMA n-half1, BAR}.
#define KTILE(B_, kt) do { \
    bf16x8 aF[4], bF[4]; \
    const char* ab = sm + (B_) * 16384 + aBase; \
    const char* bb = sm + (B_) * 8192 + bBase; \
    _Pragma("unroll") for (int m = 0; m < 4; ++m) aF[m] = *(const bf16x8*)(ab + m * 1024); \
    _Pragma("unroll") for (int n = 0; n < 4; ++n) bF[n] = *(const bf16x8*)(bb + n * 1024); \
    __builtin_amdgcn_s_setprio(1); \
    _Pragma("unroll") for (int m = 0; m < 4; ++m) { MFMA_(aF[m], bF[0], acc[m][0]); MFMA_(aF[m], bF[1], acc[m][1]); } \
    __builtin_amdgcn_s_setprio(0); \
    LGKM0(); SCHED0(); \
    BAR(); \
    { const int kSt = ((kt) + 2 < 32) ? ((kt) + 2) * 32 : 0; STG(B_, kSt); } \
    VMC(3); SCHED0(); \
    __builtin_amdgcn_s_setprio(1); \
    _Pragma("unroll") for (int m = 0; m < 4; ++m) { MFMA_(aF[m], bF[2], acc[m][2]); MFMA_(aF[m], bF[3], acc[m][3]); } \
    __builtin_amdgcn_s_setprio(0); \
    BAR(); \
  } while (0)

  for (int kt = 0; kt < 32; kt += 2) {
    KTILE(0, kt);
    KTILE(1, kt + 1);
  }

  // epilogue: per-row max-dot over 4 n-frags + 16 col-lanes -> red -> atomic
  float (*red)[2] = (float (*)[2])(sm + 49152);
#pragma unroll
  for (int m = 0; m < 4; ++m) {
#pragma unroll
    for (int rr = 0; rr < 4; ++rr) {
      float v = fmaxf(fmaxf(acc[m][0][rr], acc[m][1][rr]), fmaxf(acc[m][2][rr], acc[m][3][rr]));
      v = fmaxf(v, __shfl_xor(v, 1, 64));
      v = fmaxf(v, __shfl_xor(v, 2, 64));
      v = fmaxf(v, __shfl_xor(v, 4, 64));
      v = fmaxf(v, __shfl_xor(v, 8, 64));
      if (lrow == 0) red[wr * 64 + m * 16 + lgrp * 4 + rr][wc] = v;
    }
  }
  BAR();
  if (tid < 256) {
    const float vv = fmaxf(red[tid][0], red[tid][1]);
    const float d = sqrtf(fmaxf(2.0f - 2.0f * vv, 1e-12f));
    // all published values are negative: uint atomicMin == float max == -min dist
    atomicMin((unsigned int*)&out[(size_t)(rowBase + tid) * TASKS + task],
              __float_as_uint(-d));
  }
#undef KTILE
#undef STG
}

extern "C" void kernel_launch(void* const* d_in, const int* in_sizes, int n_in,
                              void* d_out, int out_size, void* d_ws, size_t ws_size,
                              hipStream_t stream) {
  const float* X = (const float*)d_in[0];   // (8192, 1024) fp32
  const float* W = (const float*)d_in[1];   // (5120, 1024) fp32
  float* out = (float*)d_out;               // (8192, 20) fp32

  unsigned short* Xn = (unsigned short*)d_ws;
  unsigned short* Wn = (unsigned short*)((char*)d_ws + (size_t)M_TOTAL * KDIM * 2);

  init_out_kernel<<<(M_TOTAL * TASKS + 255) / 256, 256, 0, stream>>>(out);
  norm_rows_kernel<<<M_TOTAL, 256, 0, stream>>>(X, Xn);
  norm_rows_kernel<<<TASKS * SBUF, 256, 0, stream>>>(W, Wn);
  gemm_min_kernel<<<1280, 512, 0, stream>>>(Xn, Wn, out);
}